// Round 1
// baseline (4924.991 us; speedup 1.0000x reference)
//
#include <hip/hip_runtime.h>
#include <cmath>

// Problem constants (from reference): x (B,D,T) fp32, codebooks (L,K,D) fp32
constexpr int Bb = 32, Dd = 256, Tt = 2048, Ll = 8, Kk = 1024;

// Tiling
constexpr int VT = 64;    // vectors per block (consecutive t, one b)
constexpr int KT = 64;    // codes per k-tile
constexpr int DC = 32;    // d-chunk staged per step
constexpr int RROW = 260; // padded residual row (mult of 4 for float4; 4*260 % 32 == 16 -> 2-way max)
constexpr int WROW = 68;  // padded Wt row (mult of 4; tx*4 stride -> 2-way max)

// ---------------------------------------------------------------------------
// wnorm[l][k] = sum_d W[l][k][d]^2  — one wave per code
__global__ void wnorm_kernel(const float* __restrict__ cb, float* __restrict__ wn) {
    int code = blockIdx.x;           // 0 .. L*K-1
    int lane = threadIdx.x;          // 0 .. 63
    const float4* w = (const float4*)(cb + (size_t)code * Dd);
    float4 v = w[lane];              // 64 lanes * 4 = 256 dims
    float s = v.x * v.x + v.y * v.y + v.z * v.z + v.w * v.w;
#pragma unroll
    for (int off = 32; off > 0; off >>= 1) s += __shfl_down(s, off, 64);
    if (lane == 0) wn[code] = s;
}

// ---------------------------------------------------------------------------
// Fused residual-VQ: all 8 layers in one kernel; residual persists in LDS.
__launch_bounds__(256, 2)
__global__ void rvq_kernel(const float* __restrict__ x, const float* __restrict__ cb,
                           const float* __restrict__ wn,
                           float* __restrict__ out, float* __restrict__ oidx) {
    __shared__ __align__(16) float R[VT * RROW];        // 66560 B residual tile
    __shared__ __align__(16) float pool[DC * WROW];     // 8704 B: Wt tile / argmin scratch
    __shared__ float rnorm_s[VT];
    __shared__ int   sidx[VT];

    const int tid = threadIdx.x;
    const int tx = tid & 15;         // k micro-group (4 codes)
    const int ty = tid >> 4;         // v micro-group (4 vectors)
    const int b = blockIdx.x >> 5;   // 32 t-tiles per batch row
    const int t0 = (blockIdx.x & 31) * VT;

    // ---- stage residual: R[v][d] = x[b][d][t0+v] (coalesced along t) ----
    {
        const int v = tid & 63, d0 = (tid >> 6) * 64;
        const float* xb = x + (size_t)b * Dd * Tt + t0 + v;
        for (int dd = 0; dd < 64; ++dd)
            R[v * RROW + d0 + dd] = xb[(size_t)(d0 + dd) * Tt];
    }

    for (int l = 0; l < Ll; ++l) {
        __syncthreads();  // residual stable (staging or previous layer's update)

        // |r|^2 per vector
        if (tid < VT) {
            const float4* rp = (const float4*)(R + tid * RROW);
            float s = 0.f;
            for (int i = 0; i < Dd / 4; ++i) {
                float4 r4 = rp[i];
                s += r4.x * r4.x + r4.y * r4.y + r4.z * r4.z + r4.w * r4.w;
            }
            rnorm_s[tid] = s;
        }

        float bestd[4];
        int   besti[4];
#pragma unroll
        for (int i = 0; i < 4; ++i) { bestd[i] = __builtin_inff(); besti[i] = 0; }

        const float* cbl = cb + (size_t)l * Kk * Dd;
        const float* wnl = wn + l * Kk;

        for (int kt = 0; kt < Kk / KT; ++kt) {
            float acc[4][4] = {};
            for (int dc = 0; dc < Dd / DC; ++dc) {
                __syncthreads();  // also covers rnorm_s write on first iteration
                // stage Wt[dd][k] = cbl[kt*KT+k][dc*DC+dd] (transpose, coalesced in d)
                {
                    const int kk = tid >> 5, ddm = tid & 31;
                    const float* src = cbl + (size_t)(kt * KT) * Dd + dc * DC + ddm;
#pragma unroll
                    for (int k8 = 0; k8 < 8; ++k8) {
                        int k = k8 * 8 + kk;
                        pool[ddm * WROW + k] = src[(size_t)k * Dd];
                    }
                }
                __syncthreads();
                // 4x4 register micro-tile, float4 LDS reads
#pragma unroll
                for (int dd = 0; dd < DC; dd += 4) {
                    float4 r4[4], w4[4];
#pragma unroll
                    for (int i = 0; i < 4; ++i)
                        r4[i] = *(const float4*)(R + (ty * 4 + i) * RROW + dc * DC + dd);
#pragma unroll
                    for (int p = 0; p < 4; ++p)
                        w4[p] = *(const float4*)(pool + (dd + p) * WROW + tx * 4);
#pragma unroll
                    for (int i = 0; i < 4; ++i) {
                        const float* rr = (const float*)&r4[i];
#pragma unroll
                        for (int p = 0; p < 4; ++p) {
                            const float rv = rr[p];
                            const float* ww = (const float*)&w4[p];
                            acc[i][0] = fmaf(rv, ww[0], acc[i][0]);
                            acc[i][1] = fmaf(rv, ww[1], acc[i][1]);
                            acc[i][2] = fmaf(rv, ww[2], acc[i][2]);
                            acc[i][3] = fmaf(rv, ww[3], acc[i][3]);
                        }
                    }
                }
            }
            // distances for this k-tile; strict-less + ascending k = first-occurrence argmin
#pragma unroll
            for (int i = 0; i < 4; ++i) {
                const float rn = rnorm_s[ty * 4 + i];
#pragma unroll
                for (int j = 0; j < 4; ++j) {
                    const int k = kt * KT + tx * 4 + j;
                    const float dist = (rn - 2.0f * acc[i][j]) + wnl[k];  // matches ref expr order
                    if (dist < bestd[i]) { bestd[i] = dist; besti[i] = k; }
                }
            }
        }

        // ---- cross-thread argmin (overlay scratch on Wt pool) ----
        __syncthreads();
        float* red_d = pool;
        int*   red_i = (int*)(pool + 1024);
#pragma unroll
        for (int i = 0; i < 4; ++i) {
            red_d[(ty * 4 + i) * 16 + tx] = bestd[i];
            red_i[(ty * 4 + i) * 16 + tx] = besti[i];
        }
        __syncthreads();
        if (tid < VT) {
            float bd = __builtin_inff();
            int bi = 0x7fffffff;
            for (int t = 0; t < 16; ++t) {
                float dcur = red_d[tid * 16 + t];
                int   icur = red_i[tid * 16 + t];
                if (dcur < bd || (dcur == bd && icur < bi)) { bd = dcur; bi = icur; }
            }
            sidx[tid] = bi;
            // indices output (B, L, T), written as float (whole d_out is fp32)
            oidx[((size_t)b * Ll + l) * Tt + t0 + tid] = (float)bi;
        }
        __syncthreads();

        // ---- residual update: R[v][d] -= W[l][sidx[v]][d] ----
        for (int v = 0; v < VT; ++v) {
            const float* q = cbl + (size_t)sidx[v] * Dd;
            R[v * RROW + tid] -= q[tid];   // tid == d, D == 256 == blockDim
        }
    }

    __syncthreads();
    // ---- out = x - final residual, (B,D,T) layout, coalesced along t ----
    {
        const int v = tid & 63, d0 = (tid >> 6) * 64;
        const float* xb = x + (size_t)b * Dd * Tt + t0 + v;
        float* ob = out + (size_t)b * Dd * Tt + t0 + v;
        for (int dd = 0; dd < 64; ++dd) {
            int d = d0 + dd;
            ob[(size_t)d * Tt] = xb[(size_t)d * Tt] - R[v * RROW + d];
        }
    }
}

// ---------------------------------------------------------------------------
extern "C" void kernel_launch(void* const* d_in, const int* in_sizes, int n_in,
                              void* d_out, int out_size, void* d_ws, size_t ws_size,
                              hipStream_t stream) {
    const float* x  = (const float*)d_in[0];   // (B, D, T) fp32
    const float* cb = (const float*)d_in[1];   // (L, K, D) fp32
    float* out  = (float*)d_out;                       // (B, D, T) fp32
    float* oidx = out + (size_t)Bb * Dd * Tt;          // (B, L, T) as fp32 values
    float* wnbuf = (float*)d_ws;                       // L*K floats (ws re-poisoned every call)

    wnorm_kernel<<<Ll * Kk, 64, 0, stream>>>(cb, wnbuf);
    rvq_kernel<<<(Bb * Tt) / VT, 256, 0, stream>>>(x, cb, wnbuf, out, oidx);
}

// Round 3
// 1158.263 us; speedup vs baseline: 4.2521x; 4.2521x over previous
//
#include <hip/hip_runtime.h>
#include <cmath>

// Problem: x (B,D,T) fp32, codebooks (L,K,D) fp32 -> out (B,D,T), indices (B,L,T)
constexpr int Bb = 32, Dd = 256, Tt = 2048, Ll = 8, Kk = 1024;
constexpr int VT = 64;            // vectors (rows) per block
constexpr int KT = 64;            // codes per k-tile
constexpr int ROWU = 264;         // padded row (bf16 elems; also fp32 elems for Rcp)
constexpr int HALF_USH = KT * ROWU;          // 16896 ushorts = 33792 B per split block
constexpr int TILE_BYTES = 2 * HALF_USH * 2; // 67584 B (hi block + lo block)
constexpr int CHUNKS = TILE_BYTES / 16 / 64; // 66 wave-calls of 1 KB

typedef __attribute__((ext_vector_type(8))) short short8;
typedef __attribute__((ext_vector_type(4))) float f32x4;

__device__ __forceinline__ ushort f2bf(float x) {
    union { float f; uint32_t u; } v{x};
    uint32_t r = v.u + 0x7fffu + ((v.u >> 16) & 1u);   // RNE
    return (ushort)(r >> 16);
}
__device__ __forceinline__ float bf2f(ushort h) {
    union { uint32_t u; float f; } v{((uint32_t)h) << 16};
    return v.f;
}
__device__ __forceinline__ void gl_lds16(const void* g, void* l) {
    __builtin_amdgcn_global_load_lds(
        (const __attribute__((address_space(1))) unsigned int*)g,
        (__attribute__((address_space(3))) unsigned int*)l, 16, 0, 0);
}

// ---------------------------------------------------------------------------
// Prep: wnorm (EXACT round-1 arithmetic: float4 expr + shfl_down tree) +
// bf16 hi/lo split of codebook into padded tile-blocked layout (global layout
// == LDS layout so global_load_lds stages each tile as a flat byte copy).
__global__ void prep_kernel(const float* __restrict__ cb, float* __restrict__ wn,
                            ushort* __restrict__ sp) {
    const int code = blockIdx.x;          // 0 .. L*K-1
    const int lane = threadIdx.x;         // 0 .. 63
    const int l = code >> 10, kk = code & 1023, kt = kk >> 6, kr = kk & 63;
    const float4 v = ((const float4*)(cb + (size_t)code * Dd))[lane];
    float s = v.x * v.x + v.y * v.y + v.z * v.z + v.w * v.w;
#pragma unroll
    for (int off = 32; off > 0; off >>= 1) s += __shfl_down(s, off, 64);
    if (lane == 0) wn[code] = s;

    float f[4] = {v.x, v.y, v.z, v.w};
    ushort hs[4], ls[4];
#pragma unroll
    for (int i = 0; i < 4; ++i) {
        hs[i] = f2bf(f[i]);
        ls[i] = f2bf(f[i] - bf2f(hs[i]));
    }
    ushort* base = sp + (size_t)(l * 16 + kt) * (2 * HALF_USH) + kr * ROWU + lane * 4;
    *(ushort4*)base               = make_ushort4(hs[0], hs[1], hs[2], hs[3]);
    *(ushort4*)(base + HALF_USH)  = make_ushort4(ls[0], ls[1], ls[2], ls[3]);
}

// ---------------------------------------------------------------------------
__launch_bounds__(256, 2)
__global__ void rvq_kernel(const float* __restrict__ x, const float* __restrict__ cb,
                           const float* __restrict__ wn, const ushort* __restrict__ sp,
                           float* __restrict__ out, float* __restrict__ oidx) {
    __shared__ __align__(16) ushort Btile[2 * HALF_USH];  // 67584 B; overlaid by Rcp
    __shared__ int   sidx[VT];
    __shared__ int   cnt[VT];
    __shared__ int   cand[VT * 32];

    const int tid = threadIdx.x;
    const int w = tid >> 6, lane = tid & 63;
    const int c = lane & 15;          // MFMA: A row m / B col n
    const int q = lane >> 4;          // quad
    const int b = blockIdx.x >> 5, t0 = (blockIdx.x & 31) * VT;
    const int myrow = 16 * w + c;     // residual row owned by this lane (A layout)
    const int t_a = t0 + myrow;

    // residual registers, A-fragment layout: R_[s][j] = r[myrow][32s+8q+j]
    float R_[8][8];
    {
        const float* xb = x + (size_t)b * Dd * Tt + t_a;
#pragma unroll
        for (int s = 0; s < 8; ++s)
#pragma unroll
            for (int j = 0; j < 8; ++j)
                R_[s][j] = xb[(size_t)(32 * s + 8 * q + j) * Tt];
    }

    for (int l = 0; l < Ll; ++l) {
        const float*  cbl = cb + (size_t)l * Kk * Dd;
        const float*  wnl = wn + l * Kk;
        const ushort* spl = sp + (size_t)l * 16 * (2 * HALF_USH);

        // split residual -> bf16 hi/lo A-fragments
        short8 ah[8], al[8];
#pragma unroll
        for (int s = 0; s < 8; ++s)
#pragma unroll
            for (int j = 0; j < 8; ++j) {
                float v = R_[s][j];
                ushort h = f2bf(v);
                ah[s][j] = (short)h;
                al[s][j] = (short)f2bf(v - bf2f(h));
            }

        // per-lane top-2 over REL distance (wnorm - 2*dot; rnorm is common per
        // row so the candidate set is unchanged by dropping it)
        float d1[4], d2[4]; int i1[4], i2[4];
#pragma unroll
        for (int i = 0; i < 4; ++i) { d1[i] = __builtin_inff(); d2[i] = __builtin_inff(); i1[i] = 0; i2[i] = 0; }

        for (int kt = 0; kt < 16; ++kt) {
            __syncthreads();  // previous tile/Rcp readers done
            {   // stage hi+lo tile (flat 67584 B), wave-strided
                const char* gsrc = (const char*)spl + (size_t)kt * TILE_BYTES;
                char* ldst = (char*)Btile;
                for (int ch = w; ch < CHUNKS; ch += 4)
                    gl_lds16(gsrc + ch * 1024 + lane * 16, ldst + ch * 1024);
            }
            __syncthreads();  // staging drained (vmcnt(0) before barrier)

            float wnv[4];
#pragma unroll
            for (int sub = 0; sub < 4; ++sub) wnv[sub] = wnl[kt * 64 + sub * 16 + c];

            f32x4 hh[4], hl[4], lh[4];
#pragma unroll
            for (int sub = 0; sub < 4; ++sub) { hh[sub] = (f32x4)0.f; hl[sub] = (f32x4)0.f; lh[sub] = (f32x4)0.f; }

#pragma unroll
            for (int s = 0; s < 8; ++s) {
                const ushort* bp = Btile + s * 32 + q * 8;
                short8 bf[4];
#pragma unroll
                for (int sub = 0; sub < 4; ++sub)
                    bf[sub] = *(const short8*)(bp + (sub * 16 + c) * ROWU);        // hi
#pragma unroll
                for (int sub = 0; sub < 4; ++sub)
                    hh[sub] = __builtin_amdgcn_mfma_f32_16x16x32_bf16(ah[s], bf[sub], hh[sub], 0, 0, 0);
#pragma unroll
                for (int sub = 0; sub < 4; ++sub)
                    lh[sub] = __builtin_amdgcn_mfma_f32_16x16x32_bf16(al[s], bf[sub], lh[sub], 0, 0, 0);
#pragma unroll
                for (int sub = 0; sub < 4; ++sub)
                    bf[sub] = *(const short8*)(bp + HALF_USH + (sub * 16 + c) * ROWU);  // lo
#pragma unroll
                for (int sub = 0; sub < 4; ++sub)
                    hl[sub] = __builtin_amdgcn_mfma_f32_16x16x32_bf16(ah[s], bf[sub], hl[sub], 0, 0, 0);
            }
#pragma unroll
            for (int sub = 0; sub < 4; ++sub) {
                const int kbase = kt * 64 + sub * 16 + c;
#pragma unroll
                for (int i = 0; i < 4; ++i) {
                    float acc = hh[sub][i] + hl[sub][i] + lh[sub][i];
                    float d = fmaf(-2.f, acc, wnv[sub]);   // rel distance
                    bool lt1 = d < d1[i], lt2 = d < d2[i];
                    d2[i] = lt1 ? d1[i] : (lt2 ? d : d2[i]);
                    i2[i] = lt1 ? i1[i] : (lt2 ? kbase : i2[i]);
                    d1[i] = lt1 ? d : d1[i];
                    i1[i] = lt1 ? kbase : i1[i];
                }
            }
        }

        __syncthreads();  // all Btile reads done -> overlay exact fp32 residual
        float* Rcp = (float*)Btile;  // [64][264] fp32 = 67584 B exactly
        {
            float* dst = Rcp + myrow * ROWU + 8 * q;
#pragma unroll
            for (int s = 0; s < 8; ++s) {
                float4 lo4 = {R_[s][0], R_[s][1], R_[s][2], R_[s][3]};
                float4 hi4 = {R_[s][4], R_[s][5], R_[s][6], R_[s][7]};
                *(float4*)(dst + 32 * s)     = lo4;
                *(float4*)(dst + 32 * s + 4) = hi4;
            }
        }
        if (tid < VT) cnt[tid] = 0;

        // per-row approx min across the 16 c-lanes (same q) owning the row
        float bmin[4];
#pragma unroll
        for (int i = 0; i < 4; ++i) {
            float md = d1[i];
#pragma unroll
            for (int off = 1; off < 16; off <<= 1) {
                float od = __shfl_xor(md, off, 64);
                md = od < md ? od : md;
            }
            bmin[i] = md;
        }
        __syncthreads();  // cnt zeroed + Rcp visible

        // margin filter -> candidate lists (margin 0.20 >> approx err ~1e-4)
#pragma unroll
        for (int i = 0; i < 4; ++i) {
            const int row = 16 * w + 4 * q + i;
            const float thr = bmin[i] + 0.20f;
            if (d1[i] <= thr) { int s_ = atomicAdd(&cnt[row], 1); cand[row * 32 + s_] = i1[i]; }
            if (d2[i] <= thr) { int s_ = atomicAdd(&cnt[row], 1); cand[row * 32 + s_] = i2[i]; }
        }
        __syncthreads();

        // Final selection. cnt==1: the candidate IS the argmin. cnt>=2: rescore
        // with BIT-EXACT round-1 arithmetic (sequential ascending fmaf dot,
        // round-1 rnorm expression order, identical wnorm, identical dist expr)
        // so the chosen index replicates the proven-passing round-1 kernel.
        if (tid < VT) {
            const int row = tid;
            const int n = cnt[row];
            int bi = cand[row * 32];
            if (n > 1) {
                const float* rp = Rcp + row * ROWU;
                float rn = 0.f;
                for (int i = 0; i < Dd / 4; ++i) {
                    float4 r4 = *(const float4*)(rp + 4 * i);
                    rn += r4.x * r4.x + r4.y * r4.y + r4.z * r4.z + r4.w * r4.w;
                }
                float bd = __builtin_inff(); bi = 0x7fffffff;
                for (int j = 0; j < n; ++j) {
                    const int cc = cand[row * 32 + j];
                    const float* wp = cbl + (size_t)cc * Dd;
                    float dot = 0.f;
                    for (int d = 0; d < Dd; ++d)
                        dot = fmaf(rp[d], wp[d], dot);
                    const float dist = (rn - 2.0f * dot) + wnl[cc];
                    if (dist < bd || (dist == bd && cc < bi)) { bd = dist; bi = cc; }
                }
            }
            sidx[row] = bi;
            oidx[((size_t)b * Ll + l) * Tt + t0 + row] = (float)bi;
        }
        __syncthreads();

        // residual update in registers (exact fp32, original codebook)
        {
            const int cc = sidx[myrow];
            const float* wp = cbl + (size_t)cc * Dd + 8 * q;
#pragma unroll
            for (int s = 0; s < 8; ++s) {
                float4 w0 = *(const float4*)(wp + 32 * s);
                float4 w1 = *(const float4*)(wp + 32 * s + 4);
                R_[s][0] -= w0.x; R_[s][1] -= w0.y; R_[s][2] -= w0.z; R_[s][3] -= w0.w;
                R_[s][4] -= w1.x; R_[s][5] -= w1.y; R_[s][6] -= w1.z; R_[s][7] -= w1.w;
            }
        }
    }

    // out = x - final residual
    {
        const float* xb = x + (size_t)b * Dd * Tt + t_a;
        float* ob = out + (size_t)b * Dd * Tt + t_a;
#pragma unroll
        for (int s = 0; s < 8; ++s)
#pragma unroll
            for (int j = 0; j < 8; ++j) {
                size_t off = (size_t)(32 * s + 8 * q + j) * Tt;
                ob[off] = xb[off] - R_[s][j];
            }
    }
}

// ---------------------------------------------------------------------------
extern "C" void kernel_launch(void* const* d_in, const int* in_sizes, int n_in,
                              void* d_out, int out_size, void* d_ws, size_t ws_size,
                              hipStream_t stream) {
    const float* x  = (const float*)d_in[0];   // (B, D, T)
    const float* cb = (const float*)d_in[1];   // (L, K, D)
    float* out  = (float*)d_out;
    float* oidx = out + (size_t)Bb * Dd * Tt;  // (B, L, T) as fp32 values
    float*  wnbuf = (float*)d_ws;                          // 8192 floats
    ushort* spbuf = (ushort*)((char*)d_ws + 32768);        // split codebook, ~8.65 MB

    prep_kernel<<<Ll * Kk, 64, 0, stream>>>(cb, wnbuf, spbuf);
    rvq_kernel<<<(Bb * Tt) / VT, 256, 0, stream>>>(x, cb, wnbuf, spbuf, out, oidx);
}